// Round 7
// baseline (34159.692 us; speedup 1.0000x reference)
//
#include <hip/hip_runtime.h>

typedef _Float16 f16;
typedef __attribute__((ext_vector_type(8))) _Float16 half8;
typedef __attribute__((ext_vector_type(4))) float f32x4;
typedef __attribute__((ext_vector_type(4))) unsigned int uint4v;

#define B_   512
#define T_   256
#define TT_  320
#define KB0  33
#define KBR  64
#define NSLOT 12   // ring of 3 rounds x 4 slabs; 12 x 12KB = 144KB LDS

struct PP {
  const f16* Wt[4];
  f16* xh[4][2];
  const float* bias;
  const float* input;
  const float* cov;
  const float* Wl;
  const float* blp;
  float* out;
  unsigned* cnt;      // [1280] global stage counters (count to 256)
  unsigned* arrive;   // [1280][8] per-(stage,xcd) leader election
  unsigned* invdone;  // [8] per-xcd last-invalidated stage (monotone)
};

__device__ __forceinline__ void gload16(const void* g, void* l) {
  __builtin_amdgcn_global_load_lds((const __attribute__((address_space(1))) void*)g,
                                   (__attribute__((address_space(3))) void*)l,
                                   16, 0, 0);
}

__device__ __forceinline__ float sigf(float x) {
  return __builtin_amdgcn_rcpf(1.f + __builtin_amdgcn_exp2f(-1.44269504f * x));
}
__device__ __forceinline__ float tanhf_(float x) {
  return 2.f * __builtin_amdgcn_rcpf(1.f + __builtin_amdgcn_exp2f(-2.88539008f * x)) - 1.f;
}

// fragment-ordered xh address: slab (k/32) of [512 rows x 32 k], tile layout [m/16][lane][8]
__device__ __forceinline__ int haddr(int k, int m) {
  return (k >> 5) * 16384 + (m >> 4) * 512 + ((m & 15) + ((k & 31) >> 3) * 16) * 8 + (k & 7);
}

// counted wait + raw barrier fused in ONE asm so nothing schedules between them.
#define WAITBAR(vm) asm volatile("s_waitcnt vmcnt(" #vm ") lgkmcnt(0)\n\ts_barrier" ::: "memory")

// Persistent kernel: 256 blocks (1/CU), global lockstep gate per stage, then ONE
// L2 invalidate per XCD (dynamically-elected leader via HW_REG_XCC_ID — no
// assumption on block->XCD mapping). A/B staging uses plain CACHED loads, so the
// 64x-duplicated A-panel reads are served by each XCD's L2 (8x reuse) instead of
// streaming from the coherence point (R6's bottleneck). Producers use agent
// write-through stores so post-inv refills from L3 are fresh.
__global__ __launch_bounds__(512) void lstm_persistent(PP P)
{
  __shared__ f16 lds[NSLOT][6144];  // per slab: A = 4096 halves (8KB), B = 2048 halves (4KB)
  const int tid = threadIdx.x;
  const int ln = tid & 63, w = tid >> 6;
  const int mg = w & 1, kg = w >> 1;        // split-K wave grid: 2 m-groups x 4 k-groups
  const int nb = blockIdx.x & 63, mb = blockIdx.x >> 6;
  const int m0 = mb * 128, n0 = nb * 16;

  int xcc = 0;
  asm volatile("s_getreg_b32 %0, hwreg(HW_REG_XCC_ID)" : "=s"(xcc));
  xcc &= 7;

  float creg[4][4];                          // cell state in registers: [layer][r]
  #pragma unroll
  for (int a = 0; a < 4; ++a)
    #pragma unroll
    for (int b = 0; b < 4; ++b) creg[a][b] = 0.f;

  for (int t = 0; t < TT_; ++t) {
    const int p = t & 1, q = p ^ 1;
    #pragma unroll
    for (int l = 0; l < 4; ++l) {
      const int s = t * 4 + l;
      const f16* __restrict__ Wt = P.Wt[l];
      const int KB   = (l == 0) ? KB0 : KBR;
      const int mode = (l == 0) ? 0 : ((l == 3) ? 2 : 1);
      const int koff = (l == 0) ? 32 : 1024;
      const f16* __restrict__ src   = P.xh[l][p];
      f16* __restrict__ selfd       = P.xh[l][q];
      f16* __restrict__ nextd       = (l < 3) ? P.xh[l + 1][p] : nullptr;
      const float* __restrict__ bias4 = P.bias + l * 4096;

      // ---- global gate + once-per-XCD L2 invalidate
      if (s > 0) {
        if (tid == 0) {
          while (__hip_atomic_load(&P.cnt[s - 1], __ATOMIC_RELAXED,
                                   __HIP_MEMORY_SCOPE_AGENT) < 256u)
            __builtin_amdgcn_s_sleep(8);
          if (__hip_atomic_fetch_add(&P.arrive[(unsigned)s * 8u + xcc], 1u,
                                     __ATOMIC_RELAXED, __HIP_MEMORY_SCOPE_AGENT) == 0u) {
            __threadfence();                 // leader: wbL2 + invL2 (drop stale xh lines)
            __hip_atomic_store(&P.invdone[xcc], (unsigned)s,
                               __ATOMIC_RELAXED, __HIP_MEMORY_SCOPE_AGENT);
          } else {
            while (__hip_atomic_load(&P.invdone[xcc], __ATOMIC_RELAXED,
                                     __HIP_MEMORY_SCOPE_AGENT) < (unsigned)s)
              __builtin_amdgcn_s_sleep(2);
          }
        }
        __syncthreads();                     // orders all staging loads after the inv
      }

      // init out[b][t] = bl (agent store: visible to (t,3) atomics + (t+1,0) readers)
      if (mode == 0 && nb == 0 && tid < 128)
        __hip_atomic_store(&P.out[(size_t)(m0 + tid) * TT_ + t], P.blp[0],
                           __ATOMIC_RELAXED, __HIP_MEMORY_SCOPE_AGENT);

      auto stage_slab = [&](int slot, int kb) {
        // A-half (8KB): all 512 threads, 16B each — plain cached (L2-reused post-inv)
        if (mode == 0 && kb == 0) {
          // generate x-columns (8 real + 24 zero pad) directly in fragment order (ds_write)
          int mf = tid >> 6, r = ln & 15, kgrp = ln >> 4;
          int brow = m0 + mf * 16 + r;
          half8 v;
          #pragma unroll
          for (int j = 0; j < 8; ++j) v[j] = (f16)0.f;
          if (kgrp == 0) {
            float x0 = (t < T_) ? P.input[brow * T_ + t]
                                : __hip_atomic_load(&P.out[(size_t)brow * TT_ + (t - 1)],
                                                    __ATOMIC_RELAXED, __HIP_MEMORY_SCOPE_AGENT);
            v[0] = (f16)x0;
            const float* cp = P.cov + ((size_t)brow * TT_ + t) * 7;
            #pragma unroll
            for (int j = 1; j < 8; ++j) v[j] = (f16)cp[j - 1];
          }
          *(half8*)&lds[slot][tid * 8] = v;
        } else {
          gload16(src + (size_t)kb * 16384 + mb * 4096 + tid * 8, &lds[slot][tid * 8]);
        }
        // B-half (4KB): threads 0..255 (waves 0-3), 16B each — plain cached (static weights)
        if (tid < 256)
          gload16(Wt + ((size_t)(nb * KB + kb)) * 2048 + tid * 8, &lds[slot][4096 + tid * 8]);
      };
      auto stage_round = [&](int r) {        // 4 slabs; clamp => constant vm counts (8 / 4)
        int base = (r % 3) * 4;
        #pragma unroll
        for (int j = 0; j < 4; ++j) {
          int kb = r * 4 + j;
          if (kb >= KB) kb = KB - 1;         // phantom dup of last slab (mode0 tail only)
          stage_slab(base + j, kb);
        }
      };

      // ---- split-K pipelined GEMM (R4-proven): ring of 3 rounds, counted vmcnt
      f32x4 acc[4][4];
      #pragma unroll
      for (int m = 0; m < 4; ++m)
        #pragma unroll
        for (int g = 0; g < 4; ++g) { acc[m][g][0]=0.f; acc[m][g][1]=0.f; acc[m][g][2]=0.f; acc[m][g][3]=0.f; }

      const int R = (KB + 3) >> 2;
      stage_round(0); stage_round(1);
      for (int i = 0; i < R; ++i) {
        if (i < R - 1) { if (w < 4) WAITBAR(8); else WAITBAR(4); }
        else           { WAITBAR(0); }
        const int kb = i * 4 + kg;
        const int slot = (i % 3) * 4 + kg;
        const half8* A  = (const half8*)&lds[slot][0];
        const half8* Bp = (const half8*)&lds[slot][4096];
        const bool live = (kb < KB);         // wave-uniform (mode0 last round, kg>0)
        half8 a0, a1, a2, a3, b0, b1, b2, b3;
        if (live) {
          a0 = A[(mg * 4 + 0) * 64 + ln];
          a1 = A[(mg * 4 + 1) * 64 + ln];
          a2 = A[(mg * 4 + 2) * 64 + ln];
          a3 = A[(mg * 4 + 3) * 64 + ln];
          b0 = Bp[ln]; b1 = Bp[64 + ln]; b2 = Bp[128 + ln]; b3 = Bp[192 + ln];
        }
        if (i + 2 < R) stage_round(i + 2);
        if (live) {
          acc[0][0] = __builtin_amdgcn_mfma_f32_16x16x32_f16(a0, b0, acc[0][0], 0, 0, 0);
          acc[0][1] = __builtin_amdgcn_mfma_f32_16x16x32_f16(a0, b1, acc[0][1], 0, 0, 0);
          acc[0][2] = __builtin_amdgcn_mfma_f32_16x16x32_f16(a0, b2, acc[0][2], 0, 0, 0);
          acc[0][3] = __builtin_amdgcn_mfma_f32_16x16x32_f16(a0, b3, acc[0][3], 0, 0, 0);
          acc[1][0] = __builtin_amdgcn_mfma_f32_16x16x32_f16(a1, b0, acc[1][0], 0, 0, 0);
          acc[1][1] = __builtin_amdgcn_mfma_f32_16x16x32_f16(a1, b1, acc[1][1], 0, 0, 0);
          acc[1][2] = __builtin_amdgcn_mfma_f32_16x16x32_f16(a1, b2, acc[1][2], 0, 0, 0);
          acc[1][3] = __builtin_amdgcn_mfma_f32_16x16x32_f16(a1, b3, acc[1][3], 0, 0, 0);
          acc[2][0] = __builtin_amdgcn_mfma_f32_16x16x32_f16(a2, b0, acc[2][0], 0, 0, 0);
          acc[2][1] = __builtin_amdgcn_mfma_f32_16x16x32_f16(a2, b1, acc[2][1], 0, 0, 0);
          acc[2][2] = __builtin_amdgcn_mfma_f32_16x16x32_f16(a2, b2, acc[2][2], 0, 0, 0);
          acc[2][3] = __builtin_amdgcn_mfma_f32_16x16x32_f16(a2, b3, acc[2][3], 0, 0, 0);
          acc[3][0] = __builtin_amdgcn_mfma_f32_16x16x32_f16(a3, b0, acc[3][0], 0, 0, 0);
          acc[3][1] = __builtin_amdgcn_mfma_f32_16x16x32_f16(a3, b1, acc[3][1], 0, 0, 0);
          acc[3][2] = __builtin_amdgcn_mfma_f32_16x16x32_f16(a3, b2, acc[3][2], 0, 0, 0);
          acc[3][3] = __builtin_amdgcn_mfma_f32_16x16x32_f16(a3, b3, acc[3][3], 0, 0, 0);
        }
      }

      // ---- split-K reduction via LDS scratch (slabs dead; vmcnt==0)
      __syncthreads();
      float* red = (float*)&lds[0][0];
      #pragma unroll
      for (int m = 0; m < 4; ++m)
        #pragma unroll
        for (int g = 0; g < 4; ++g)
          *(f32x4*)&red[w * 4096 + (m * 4 + g) * 256 + ln * 4] = acc[m][g];
      __syncthreads();
      f32x4 facc[4];
      #pragma unroll
      for (int g = 0; g < 4; ++g) { facc[g][0]=0.f; facc[g][1]=0.f; facc[g][2]=0.f; facc[g][3]=0.f; }
      const int mgw = w >> 2, mlw = w & 3;   // final wave w owns m-frag w
      #pragma unroll
      for (int kg2 = 0; kg2 < 4; ++kg2) {
        const int wsrc = kg2 * 2 + mgw;
        #pragma unroll
        for (int g = 0; g < 4; ++g) {
          f32x4 pv = *(const f32x4*)&red[wsrc * 4096 + (mlw * 4 + g) * 256 + ln * 4];
          facc[g][0] += pv[0]; facc[g][1] += pv[1]; facc[g][2] += pv[2]; facc[g][3] += pv[3];
        }
      }

      // ---- epilogue: lane holds gates for rows rowb..rowb+3, col n0+(ln&15)
      const int col = n0 + (ln & 15);
      const int rowb = m0 + w * 16 + (ln >> 4) * 4;
      const float bi  = bias4[col];
      const float bff = bias4[1024 + col];
      const float bgg = bias4[2048 + col];
      const float bo  = bias4[3072 + col];
      const float wl  = (mode == 2) ? P.Wl[col] : 0.f;
      #pragma unroll
      for (int r = 0; r < 4; ++r) {
        const int row = rowb + r;
        float gi = facc[0][r] + bi;
        float gf = facc[1][r] + bff;
        float gg = facc[2][r] + bgg;
        float go = facc[3][r] + bo;
        float cn = sigf(gf) * creg[l][r] + sigf(gi) * tanhf_(gg);
        float h  = sigf(go) * tanhf_(cn);
        creg[l][r] = cn;                     // cell state stays in registers
        f16 hh = (f16)h;
        unsigned short hbits = __builtin_bit_cast(unsigned short, hh);
        // agent-scope (write-through) stores: fresh in L3 for post-inv refills
        __hip_atomic_store((unsigned short*)&selfd[haddr(koff + col, row)], hbits,
                           __ATOMIC_RELAXED, __HIP_MEMORY_SCOPE_AGENT);
        if (mode != 2) {
          __hip_atomic_store((unsigned short*)&nextd[haddr(col, row)], hbits,
                             __ATOMIC_RELAXED, __HIP_MEMORY_SCOPE_AGENT);
        } else {
          float val = h * wl;                // fused out-projection partial
          val += __shfl_xor(val, 1);
          val += __shfl_xor(val, 2);
          val += __shfl_xor(val, 4);
          val += __shfl_xor(val, 8);
          if ((ln & 15) == 0) atomicAdd(P.out + (size_t)row * TT_ + t, val);
        }
      }

      // ---- release: syncthreads drains every wave's stores (agent stores acked at
      // coherence point at vmcnt0), then signal the single global stage counter.
      __syncthreads();
      if (tid == 0)
        __hip_atomic_fetch_add(&P.cnt[s], 1u,
                               __ATOMIC_RELAXED, __HIP_MEMORY_SCOPE_AGENT);
    }
  }
}

__global__ void zero_ws(uint4v* pz, int n)   // zero xh buffers + sync vars
{
  int i = blockIdx.x * 256 + threadIdx.x;
  if (i < n) { uint4v z; z[0] = 0u; z[1] = 0u; z[2] = 0u; z[3] = 0u; pz[i] = z; }
}

__global__ void pack_weights(const float* __restrict__ Wih0, const float* __restrict__ Whh0,
                             const float* __restrict__ Wihr, const float* __restrict__ Whhr,
                             f16* __restrict__ Wt0, f16* __restrict__ Wt1,
                             f16* __restrict__ Wt2, f16* __restrict__ Wt3)
{
  const int layer = blockIdx.y;
  const size_t e = (size_t)blockIdx.x * 256 + threadIdx.x;
  const int KB = layer ? KBR : KB0;
  if (e >= (size_t)64 * KB * 2048) return;
  const int panel = (int)(e >> 11), win = (int)(e & 2047);
  const int g = win >> 9, lane = (win >> 3) & 63, j = win & 7;
  const int nb = panel / KB, kb = panel - nb * KB;
  const int n = nb * 16 + (lane & 15);
  const int k = kb * 32 + (lane >> 4) * 8 + j;
  const int jr = g * 1024 + n;                       // row in [4H][*] weight (gate-major)
  float v;
  if (layer == 0) {
    if (k < 8)       v = Wih0[jr * 8 + k];
    else if (k < 32) v = 0.f;
    else             v = Whh0[(size_t)jr * 1024 + (k - 32)];
  } else {
    const size_t base = (size_t)(layer - 1) * 4096 * 1024 + (size_t)jr * 1024;
    v = (k < 1024) ? Wihr[base + k] : Whhr[base + (k - 1024)];
  }
  f16 hv = (f16)v;
  if      (layer == 0) Wt0[e] = hv;
  else if (layer == 1) Wt1[e] = hv;
  else if (layer == 2) Wt2[e] = hv;
  else                 Wt3[e] = hv;
}

__global__ void pack_bias(const float* __restrict__ bih0, const float* __restrict__ bhh0,
                          const float* __restrict__ bihr, const float* __restrict__ bhhr,
                          float* __restrict__ bias)
{
  const int idx = blockIdx.x * 256 + threadIdx.x;    // 16384 = 4 layers x 4096
  const int lyr = idx >> 12, j = idx & 4095;
  bias[idx] = (lyr == 0) ? (bih0[j] + bhh0[j])
                         : (bihr[(lyr - 1) * 4096 + j] + bhhr[(lyr - 1) * 4096 + j]);
}

extern "C" void kernel_launch(void* const* d_in, const int* in_sizes, int n_in,
                              void* d_out, int out_size, void* d_ws, size_t ws_size,
                              hipStream_t stream)
{
  const float* input = (const float*)d_in[0];
  const float* cov   = (const float*)d_in[1];
  const float* Wih0  = (const float*)d_in[2];
  const float* Whh0  = (const float*)d_in[3];
  const float* bih0  = (const float*)d_in[4];
  const float* bhh0  = (const float*)d_in[5];
  const float* Wihr  = (const float*)d_in[6];
  const float* Whhr  = (const float*)d_in[7];
  const float* bihr  = (const float*)d_in[8];
  const float* bhhr  = (const float*)d_in[9];
  const float* Wl    = (const float*)d_in[10];
  const float* blp   = (const float*)d_in[11];
  float* out = (float*)d_out;
  char* ws = (char*)d_ws;

  // workspace layout (bytes):
  //   xh0[2] @ 0        (2 x 1,081,344)   ping-pong fragment-ordered A buffers
  //   xh1[2] @ 2162688  (2 x 2,097,152)
  //   xh2[2] @ 6356992  (2 x 2,097,152)
  //   xh3[2] @ 10551296 (2 x 2,097,152)
  //   cnt    @ 14745600 (5,120)           [1280] global stage counters
  //   arrive @ 14750720 (40,960)          [1280][8] leader election
  //   invdone@ 14791680 (32)              [8] per-xcd inv progress
  //   bias   @ 23134208 (65,536)
  //   Wt0    @ 23199744 (8,650,752)       f16 fragment-packed weights
  //   Wt1    @ 31850496 (16,777,216)
  //   Wt2    @ 48627712 (16,777,216)
  //   Wt3    @ 65404928 (16,777,216)      total 82,182,144
  const size_t XH0 = 1081344, XHR = 2097152;
  PP Pv;
  Pv.xh[0][0] = (f16*)(ws);            Pv.xh[0][1] = (f16*)(ws + XH0);
  Pv.xh[1][0] = (f16*)(ws + 2162688);  Pv.xh[1][1] = (f16*)(ws + 2162688 + XHR);
  Pv.xh[2][0] = (f16*)(ws + 6356992);  Pv.xh[2][1] = (f16*)(ws + 6356992 + XHR);
  Pv.xh[3][0] = (f16*)(ws + 10551296); Pv.xh[3][1] = (f16*)(ws + 10551296 + XHR);
  Pv.cnt     = (unsigned*)(ws + 14745600);
  Pv.arrive  = (unsigned*)(ws + 14750720);
  Pv.invdone = (unsigned*)(ws + 14791680);
  float* bias   = (float*)(ws + 23134208);
  f16* Wt0 = (f16*)(ws + 23199744);
  f16* Wt1 = (f16*)(ws + 31850496);
  f16* Wt2 = (f16*)(ws + 48627712);
  f16* Wt3 = (f16*)(ws + 65404928);
  Pv.Wt[0] = Wt0; Pv.Wt[1] = Wt1; Pv.Wt[2] = Wt2; Pv.Wt[3] = Wt3;
  Pv.bias = bias; Pv.input = input; Pv.cov = cov;
  Pv.Wl = Wl; Pv.blp = blp; Pv.out = out;

  pack_weights<<<dim3(32768, 4), 256, 0, stream>>>(Wih0, Whh0, Wihr, Whhr, Wt0, Wt1, Wt2, Wt3);
  pack_bias<<<64, 256, 0, stream>>>(bih0, bhh0, bihr, bhhr, bias);
  // zero xh (h0 = 0; t==0 reads zero slabs through the normal pipeline) + sync vars
  zero_ws<<<3612, 256, 0, stream>>>((uint4v*)ws, 14791712 / 16);

  void* args[] = { &Pv };
  hipLaunchCooperativeKernel(reinterpret_cast<void*>(&lstm_persistent),
                             dim3(256), dim3(512), args, 0, stream);
}

// Round 8
// 18895.781 us; speedup vs baseline: 1.8078x; 1.8078x over previous
//
#include <hip/hip_runtime.h>

typedef _Float16 f16;
typedef __attribute__((ext_vector_type(8))) _Float16 half8;
typedef __attribute__((ext_vector_type(4))) float f32x4;
typedef __attribute__((ext_vector_type(4))) unsigned int uint4v;

#define B_   512
#define T_   256
#define TT_  320
#define KB0  33
#define KBR  64
#define NSLOT 12   // ring of 3 rounds x 4 slabs; 12 x 12KB = 144KB LDS

struct PP {
  const f16* Wt[4];
  f16* xh[4][2];
  float* cst;         // [4][512][1024] fp32 cell state (zeroed per call)
  const float* bias;
  const float* input;
  const float* cov;
  const float* Wl;
  const float* blp;
  float* out;
};

__device__ __forceinline__ void gload16(const void* g, void* l) {
  __builtin_amdgcn_global_load_lds((const __attribute__((address_space(1))) void*)g,
                                   (__attribute__((address_space(3))) void*)l,
                                   16, 0, 0);
}

__device__ __forceinline__ float sigf(float x) {
  return __builtin_amdgcn_rcpf(1.f + __builtin_amdgcn_exp2f(-1.44269504f * x));
}
__device__ __forceinline__ float tanhf_(float x) {
  return 2.f * __builtin_amdgcn_rcpf(1.f + __builtin_amdgcn_exp2f(-2.88539008f * x)) - 1.f;
}

// fragment-ordered xh address: slab (k/32) of [512 rows x 32 k], tile layout [m/16][lane][8]
__device__ __forceinline__ int haddr(int k, int m) {
  return (k >> 5) * 16384 + (m >> 4) * 512 + ((m & 15) + ((k & 31) >> 3) * 16) * 8 + (k & 7);
}

// counted wait + raw barrier fused in ONE asm so nothing schedules between them.
// lgkmcnt(0) before s_barrier: my ds reads/writes retired => post-barrier DMA into a
// recycled slot can't race a still-queued access (buffer-reuse hazard).
#define WAITBAR(vm) asm volatile("s_waitcnt vmcnt(" #vm ") lgkmcnt(0)\n\ts_barrier" ::: "memory")

// One dispatch runs the anti-diagonal d: cells (l, t=d-l) for l in [lbeg,lend],
// 0 <= t < tlim. Cells within a diagonal are INDEPENDENT (deps (l-1,t) and (l,t-1)
// are both in diagonal d-1 = the previous dispatch), and ping-pong xh buffers make
// every intra-dispatch write target a buffer nobody reads this dispatch. So there is
// NO in-kernel cross-block sync: dispatch boundaries provide coherence (the cheapest
// mechanism on this chip per R5-R7 measurements). Future phase (t>=256, out-feedback
// serializes the layer chain) uses single-cell dispatches: lbeg==lend.
__global__ __launch_bounds__(512) void lstm_cells(PP P, int d, int lbeg, int lend, int tlim)
{
  __shared__ f16 lds[NSLOT][6144];  // per slab: A = 4096 halves (8KB), B = 2048 halves (4KB)
  const int tid = threadIdx.x;
  const int ln = tid & 63, w = tid >> 6;
  const int mg = w & 1, kg = w >> 1;        // split-K wave grid: 2 m-groups x 4 k-groups
  const int nb = blockIdx.x & 63, mb = blockIdx.x >> 6;
  const int m0 = mb * 128, n0 = nb * 16;

  for (int l = lbeg; l <= lend; ++l) {
    const int t = d - l;
    if (t < 0 || t >= tlim) continue;

    const int p = t & 1, q = p ^ 1;
    const f16* __restrict__ Wt = P.Wt[l];
    const int KB   = (l == 0) ? KB0 : KBR;
    const int mode = (l == 0) ? 0 : ((l == 3) ? 2 : 1);
    const int koff = (l == 0) ? 32 : 1024;
    const f16* __restrict__ src   = P.xh[l][p];
    f16* __restrict__ selfd       = P.xh[l][q];
    f16* __restrict__ nextd       = (l < 3) ? P.xh[l + 1][p] : nullptr;
    const float* __restrict__ bias4 = P.bias + l * 4096;
    float* __restrict__ cst = P.cst + (size_t)l * 524288;

    // init out[b][t] = bl (ordered before layer3's atomics: they happen 3 dispatches later)
    if (mode == 0 && nb == 0 && tid < 128) P.out[(size_t)(m0 + tid) * TT_ + t] = P.blp[0];

    auto stage_slab = [&](int slot, int kb) {
      // A-half (8KB): all 512 threads, 16B each
      if (mode == 0 && kb == 0) {
        // generate x-columns (8 real + 24 zero pad) directly in fragment order (ds_write)
        int mf = tid >> 6, r = ln & 15, kgrp = ln >> 4;
        int brow = m0 + mf * 16 + r;
        half8 v;
        #pragma unroll
        for (int j = 0; j < 8; ++j) v[j] = (f16)0.f;
        if (kgrp == 0) {
          float x0 = (t < T_) ? P.input[brow * T_ + t] : P.out[(size_t)brow * TT_ + (t - 1)];
          v[0] = (f16)x0;
          const float* cp = P.cov + ((size_t)brow * TT_ + t) * 7;
          #pragma unroll
          for (int j = 1; j < 8; ++j) v[j] = (f16)cp[j - 1];
        }
        *(half8*)&lds[slot][tid * 8] = v;
      } else {
        gload16(src + (size_t)kb * 16384 + mb * 4096 + tid * 8, &lds[slot][tid * 8]);
      }
      // B-half (4KB): threads 0..255 (waves 0-3), 16B each
      if (tid < 256)
        gload16(Wt + ((size_t)(nb * KB + kb)) * 2048 + tid * 8, &lds[slot][4096 + tid * 8]);
    };
    auto stage_round = [&](int r) {          // 4 slabs; clamp => constant vm counts (8 / 4)
      int base = (r % 3) * 4;
      #pragma unroll
      for (int j = 0; j < 4; ++j) {
        int kb = r * 4 + j;
        if (kb >= KB) kb = KB - 1;           // phantom dup of last slab (mode0 tail only)
        stage_slab(base + j, kb);
      }
    };

    // ---- split-K pipelined GEMM (R4-proven): ring of 3 rounds, counted vmcnt
    f32x4 acc[4][4];
    #pragma unroll
    for (int m = 0; m < 4; ++m)
      #pragma unroll
      for (int g = 0; g < 4; ++g) { acc[m][g][0]=0.f; acc[m][g][1]=0.f; acc[m][g][2]=0.f; acc[m][g][3]=0.f; }

    const int R = (KB + 3) >> 2;
    stage_round(0); stage_round(1);
    for (int i = 0; i < R; ++i) {
      if (i < R - 1) { if (w < 4) WAITBAR(8); else WAITBAR(4); }
      else           { WAITBAR(0); }
      const int kb = i * 4 + kg;
      const int slot = (i % 3) * 4 + kg;
      const half8* A  = (const half8*)&lds[slot][0];
      const half8* Bp = (const half8*)&lds[slot][4096];
      const bool live = (kb < KB);           // wave-uniform (mode0 last round, kg>0)
      half8 a0, a1, a2, a3, b0, b1, b2, b3;
      if (live) {
        a0 = A[(mg * 4 + 0) * 64 + ln];
        a1 = A[(mg * 4 + 1) * 64 + ln];
        a2 = A[(mg * 4 + 2) * 64 + ln];
        a3 = A[(mg * 4 + 3) * 64 + ln];
        b0 = Bp[ln]; b1 = Bp[64 + ln]; b2 = Bp[128 + ln]; b3 = Bp[192 + ln];
      }
      if (i + 2 < R) stage_round(i + 2);
      if (live) {
        acc[0][0] = __builtin_amdgcn_mfma_f32_16x16x32_f16(a0, b0, acc[0][0], 0, 0, 0);
        acc[0][1] = __builtin_amdgcn_mfma_f32_16x16x32_f16(a0, b1, acc[0][1], 0, 0, 0);
        acc[0][2] = __builtin_amdgcn_mfma_f32_16x16x32_f16(a0, b2, acc[0][2], 0, 0, 0);
        acc[0][3] = __builtin_amdgcn_mfma_f32_16x16x32_f16(a0, b3, acc[0][3], 0, 0, 0);
        acc[1][0] = __builtin_amdgcn_mfma_f32_16x16x32_f16(a1, b0, acc[1][0], 0, 0, 0);
        acc[1][1] = __builtin_amdgcn_mfma_f32_16x16x32_f16(a1, b1, acc[1][1], 0, 0, 0);
        acc[1][2] = __builtin_amdgcn_mfma_f32_16x16x32_f16(a1, b2, acc[1][2], 0, 0, 0);
        acc[1][3] = __builtin_amdgcn_mfma_f32_16x16x32_f16(a1, b3, acc[1][3], 0, 0, 0);
        acc[2][0] = __builtin_amdgcn_mfma_f32_16x16x32_f16(a2, b0, acc[2][0], 0, 0, 0);
        acc[2][1] = __builtin_amdgcn_mfma_f32_16x16x32_f16(a2, b1, acc[2][1], 0, 0, 0);
        acc[2][2] = __builtin_amdgcn_mfma_f32_16x16x32_f16(a2, b2, acc[2][2], 0, 0, 0);
        acc[2][3] = __builtin_amdgcn_mfma_f32_16x16x32_f16(a2, b3, acc[2][3], 0, 0, 0);
        acc[3][0] = __builtin_amdgcn_mfma_f32_16x16x32_f16(a3, b0, acc[3][0], 0, 0, 0);
        acc[3][1] = __builtin_amdgcn_mfma_f32_16x16x32_f16(a3, b1, acc[3][1], 0, 0, 0);
        acc[3][2] = __builtin_amdgcn_mfma_f32_16x16x32_f16(a3, b2, acc[3][2], 0, 0, 0);
        acc[3][3] = __builtin_amdgcn_mfma_f32_16x16x32_f16(a3, b3, acc[3][3], 0, 0, 0);
      }
    }

    // ---- split-K reduction via LDS scratch (slabs dead; vmcnt==0)
    __syncthreads();
    float* red = (float*)&lds[0][0];
    #pragma unroll
    for (int m = 0; m < 4; ++m)
      #pragma unroll
      for (int g = 0; g < 4; ++g)
        *(f32x4*)&red[w * 4096 + (m * 4 + g) * 256 + ln * 4] = acc[m][g];
    __syncthreads();
    f32x4 facc[4];
    #pragma unroll
    for (int g = 0; g < 4; ++g) { facc[g][0]=0.f; facc[g][1]=0.f; facc[g][2]=0.f; facc[g][3]=0.f; }
    const int mgw = w >> 2, mlw = w & 3;     // final wave w owns m-frag w
    #pragma unroll
    for (int kg2 = 0; kg2 < 4; ++kg2) {
      const int wsrc = kg2 * 2 + mgw;
      #pragma unroll
      for (int g = 0; g < 4; ++g) {
        f32x4 pv = *(const f32x4*)&red[wsrc * 4096 + (mlw * 4 + g) * 256 + ln * 4];
        facc[g][0] += pv[0]; facc[g][1] += pv[1]; facc[g][2] += pv[2]; facc[g][3] += pv[3];
      }
    }
    __syncthreads();                         // red reads done before next cell restages LDS

    // ---- epilogue: lane holds gates for rows rowb..rowb+3, col n0+(ln&15)
    const int col = n0 + (ln & 15);
    const int rowb = m0 + w * 16 + (ln >> 4) * 4;
    const float bi  = bias4[col];
    const float bff = bias4[1024 + col];
    const float bgg = bias4[2048 + col];
    const float bo  = bias4[3072 + col];
    const float wl  = (mode == 2) ? P.Wl[col] : 0.f;
    #pragma unroll
    for (int r = 0; r < 4; ++r) {
      const int row = rowb + r;
      float gi = facc[0][r] + bi;
      float gf = facc[1][r] + bff;
      float gg = facc[2][r] + bgg;
      float go = facc[3][r] + bo;
      float* cp = cst + (size_t)row * 1024 + col;
      float cn = sigf(gf) * (*cp) + sigf(gi) * tanhf_(gg);   // c pre-zeroed per call
      float h  = sigf(go) * tanhf_(cn);
      *cp = cn;
      f16 hh = (f16)h;
      selfd[haddr(koff + col, row)] = hh;    // h(t) for this layer's next step
      if (mode != 2) {
        nextd[haddr(col, row)] = hh;         // x-part for next layer, this step
      } else {
        float val = h * wl;                  // fused out-projection partial
        val += __shfl_xor(val, 1);
        val += __shfl_xor(val, 2);
        val += __shfl_xor(val, 4);
        val += __shfl_xor(val, 8);
        if ((ln & 15) == 0) atomicAdd(P.out + (size_t)row * TT_ + t, val);
      }
    }
  }
}

__global__ void zero_ws(uint4v* pz, int n)   // zero xh buffers + cell state
{
  int i = blockIdx.x * 256 + threadIdx.x;
  if (i < n) { uint4v z; z[0] = 0u; z[1] = 0u; z[2] = 0u; z[3] = 0u; pz[i] = z; }
}

__global__ void pack_weights(const float* __restrict__ Wih0, const float* __restrict__ Whh0,
                             const float* __restrict__ Wihr, const float* __restrict__ Whhr,
                             f16* __restrict__ Wt0, f16* __restrict__ Wt1,
                             f16* __restrict__ Wt2, f16* __restrict__ Wt3)
{
  const int layer = blockIdx.y;
  const size_t e = (size_t)blockIdx.x * 256 + threadIdx.x;
  const int KB = layer ? KBR : KB0;
  if (e >= (size_t)64 * KB * 2048) return;
  const int panel = (int)(e >> 11), win = (int)(e & 2047);
  const int g = win >> 9, lane = (win >> 3) & 63, j = win & 7;
  const int nb = panel / KB, kb = panel - nb * KB;
  const int n = nb * 16 + (lane & 15);
  const int k = kb * 32 + (lane >> 4) * 8 + j;
  const int jr = g * 1024 + n;                       // row in [4H][*] weight (gate-major)
  float v;
  if (layer == 0) {
    if (k < 8)       v = Wih0[jr * 8 + k];
    else if (k < 32) v = 0.f;
    else             v = Whh0[(size_t)jr * 1024 + (k - 32)];
  } else {
    const size_t base = (size_t)(layer - 1) * 4096 * 1024 + (size_t)jr * 1024;
    v = (k < 1024) ? Wihr[base + k] : Whhr[base + (k - 1024)];
  }
  f16 hv = (f16)v;
  if      (layer == 0) Wt0[e] = hv;
  else if (layer == 1) Wt1[e] = hv;
  else if (layer == 2) Wt2[e] = hv;
  else                 Wt3[e] = hv;
}

__global__ void pack_bias(const float* __restrict__ bih0, const float* __restrict__ bhh0,
                          const float* __restrict__ bihr, const float* __restrict__ bhhr,
                          float* __restrict__ bias)
{
  const int idx = blockIdx.x * 256 + threadIdx.x;    // 16384 = 4 layers x 4096
  const int lyr = idx >> 12, j = idx & 4095;
  bias[idx] = (lyr == 0) ? (bih0[j] + bhh0[j])
                         : (bihr[(lyr - 1) * 4096 + j] + bhhr[(lyr - 1) * 4096 + j]);
}

extern "C" void kernel_launch(void* const* d_in, const int* in_sizes, int n_in,
                              void* d_out, int out_size, void* d_ws, size_t ws_size,
                              hipStream_t stream)
{
  const float* input = (const float*)d_in[0];
  const float* cov   = (const float*)d_in[1];
  const float* Wih0  = (const float*)d_in[2];
  const float* Whh0  = (const float*)d_in[3];
  const float* bih0  = (const float*)d_in[4];
  const float* bhh0  = (const float*)d_in[5];
  const float* Wihr  = (const float*)d_in[6];
  const float* Whhr  = (const float*)d_in[7];
  const float* bihr  = (const float*)d_in[8];
  const float* bhhr  = (const float*)d_in[9];
  const float* Wl    = (const float*)d_in[10];
  const float* blp   = (const float*)d_in[11];
  float* out = (float*)d_out;
  char* ws = (char*)d_ws;

  // workspace layout (bytes):
  //   xh0[2] @ 0        (2 x 1,081,344)   ping-pong fragment-ordered A buffers
  //   xh1[2] @ 2162688  (2 x 2,097,152)
  //   xh2[2] @ 6356992  (2 x 2,097,152)
  //   xh3[2] @ 10551296 (2 x 2,097,152)
  //   c      @ 14745600 (4 x 2,097,152)   fp32 cell state
  //   bias   @ 23134208 (65,536)
  //   Wt0    @ 23199744 (8,650,752)       f16 fragment-packed weights
  //   Wt1    @ 31850496 (16,777,216)
  //   Wt2    @ 48627712 (16,777,216)
  //   Wt3    @ 65404928 (16,777,216)      total 82,182,144
  // xh + c zeroed per call by zero_ws (same-call, stream-ordered): no cross-call state.
  const size_t XH0 = 1081344, XHR = 2097152;
  PP Pv;
  Pv.xh[0][0] = (f16*)(ws);            Pv.xh[0][1] = (f16*)(ws + XH0);
  Pv.xh[1][0] = (f16*)(ws + 2162688);  Pv.xh[1][1] = (f16*)(ws + 2162688 + XHR);
  Pv.xh[2][0] = (f16*)(ws + 6356992);  Pv.xh[2][1] = (f16*)(ws + 6356992 + XHR);
  Pv.xh[3][0] = (f16*)(ws + 10551296); Pv.xh[3][1] = (f16*)(ws + 10551296 + XHR);
  Pv.cst     = (float*)(ws + 14745600);
  float* bias = (float*)(ws + 23134208);
  f16* Wt0 = (f16*)(ws + 23199744);
  f16* Wt1 = (f16*)(ws + 31850496);
  f16* Wt2 = (f16*)(ws + 48627712);
  f16* Wt3 = (f16*)(ws + 65404928);
  Pv.Wt[0] = Wt0; Pv.Wt[1] = Wt1; Pv.Wt[2] = Wt2; Pv.Wt[3] = Wt3;
  Pv.bias = bias; Pv.input = input; Pv.cov = cov;
  Pv.Wl = Wl; Pv.blp = blp; Pv.out = out;

  pack_weights<<<dim3(32768, 4), 256, 0, stream>>>(Wih0, Whh0, Wihr, Whhr, Wt0, Wt1, Wt2, Wt3);
  pack_bias<<<64, 256, 0, stream>>>(bih0, bhh0, bihr, bhhr, bias);
  zero_ws<<<5648, 256, 0, stream>>>((uint4v*)ws, 23134208 / 16);

  // Conditioning phase (t < 256): anti-diagonal wavefront, 4 independent cells/dispatch.
  for (int dg = 0; dg <= 258; ++dg)
    lstm_cells<<<256, 512, 0, stream>>>(Pv, dg, 0, 3, T_);
  // Future phase (t >= 256): out-feedback serializes layers; one cell per dispatch.
  for (int t = T_; t < TT_; ++t)
    for (int l = 0; l < 4; ++l)
      lstm_cells<<<256, 512, 0, stream>>>(Pv, t + l, l, l, TT_);
}

// Round 9
// 17750.877 us; speedup vs baseline: 1.9244x; 1.0645x over previous
//
#include <hip/hip_runtime.h>

typedef _Float16 f16;
typedef __attribute__((ext_vector_type(8))) _Float16 half8;
typedef __attribute__((ext_vector_type(4))) float f32x4;
typedef __attribute__((ext_vector_type(4))) unsigned int uint4v;

#define B_   512
#define T_   256
#define TT_  320
#define KB0  33
#define KBR  64
#define NSLOT 12   // small kernel: ring of 3 rounds x 4 slabs; 12 x 12KB = 144KB LDS

struct PP {
  const f16* Wt[4];
  f16* xh[4][2];
  float* cst;         // [4][512][1024] fp32 cell state (zeroed per call)
  const float* bias;
  const float* input;
  const float* cov;
  const float* Wl;
  const float* blp;
  float* out;
};

__device__ __forceinline__ void gload16(const void* g, void* l) {
  __builtin_amdgcn_global_load_lds((const __attribute__((address_space(1))) void*)g,
                                   (__attribute__((address_space(3))) void*)l,
                                   16, 0, 0);
}

__device__ __forceinline__ float sigf(float x) {
  return __builtin_amdgcn_rcpf(1.f + __builtin_amdgcn_exp2f(-1.44269504f * x));
}
__device__ __forceinline__ float tanhf_(float x) {
  return 2.f * __builtin_amdgcn_rcpf(1.f + __builtin_amdgcn_exp2f(-2.88539008f * x)) - 1.f;
}

// fragment-ordered xh address: slab (k/32) of [512 rows x 32 k], tile layout [m/16][lane][8]
__device__ __forceinline__ int haddr(int k, int m) {
  return (k >> 5) * 16384 + (m >> 4) * 512 + ((m & 15) + ((k & 31) >> 3) * 16) * 8 + (k & 7);
}

// counted wait + raw barrier fused in ONE asm so nothing schedules between them.
#define WAITBAR(vm) asm volatile("s_waitcnt vmcnt(" #vm ") lgkmcnt(0)\n\ts_barrier" ::: "memory")

// ============================================================================
// BIG-TILE conditioning kernel: one dispatch = anti-diagonal d, 4 independent
// cells x 64 blocks each = 256 blocks (1/CU), all cells in parallel.
// Block tile: M128 x N64 h-cols (256 gate-cols = 4 weight panels).
// Slab (K32) = A 8KB + B 16KB; ring of 3 rounds x 2 slabs = 144KB LDS.
// Waves: 2mg x 2ng x 2kg (kg = slab parity in round); acc 4m x 8n f32x4.
// Chip staging halves vs small tile (96 vs 192 MB/cell): MFMA becomes the floor.
// ============================================================================
__global__ __launch_bounds__(512, 2) void lstm_cells_big(PP P, int d)
{
  __shared__ f16 lds[6][12288];   // 6 slabs x 24KB; reduction buffer overlays after loop
  const int tid = threadIdx.x;
  const int ln = tid & 63, w = tid >> 6;
  const int mg = w & 1, ng = (w >> 1) & 1, kg = w >> 2;
  const int cid = blockIdx.x >> 6, bb = blockIdx.x & 63;
  const int mb2 = bb >> 4, nb2 = bb & 15;
  const int m0 = mb2 * 128;

  const int l = cid, t = d - l;
  if (t < 0 || t >= T_) return;            // block-uniform

  const int p = t & 1, q = p ^ 1;
  const f16* __restrict__ Wt = P.Wt[l];
  const int KB   = (l == 0) ? KB0 : KBR;
  const int koff = (l == 0) ? 32 : 1024;
  const f16* __restrict__ src   = P.xh[l][p];
  f16* __restrict__ selfd       = P.xh[l][q];
  f16* __restrict__ nextd       = (l < 3) ? P.xh[l + 1][p] : nullptr;
  const float* __restrict__ bias4 = P.bias + l * 4096;
  float* __restrict__ cst = P.cst + (size_t)l * 524288;

  // init out[b][t] = bl (consumed by (3,t)'s atomics 3 dispatches later)
  if (l == 0 && nb2 == 0 && tid < 128) P.out[(size_t)(m0 + tid) * TT_ + t] = P.blp[0];

  auto stage_slab = [&](int slot, int kb) {
    // A-half (8KB): 512 threads x 16B
    if (l == 0 && kb == 0) {
      // x-columns (8 real + 24 zero pad) in fragment order (ds_write; conditioning => input)
      int mf = tid >> 6, r = ln & 15, kgrp = ln >> 4;
      int brow = m0 + mf * 16 + r;
      half8 v;
      #pragma unroll
      for (int j = 0; j < 8; ++j) v[j] = (f16)0.f;
      if (kgrp == 0) {
        v[0] = (f16)P.input[brow * T_ + t];
        const float* cp = P.cov + ((size_t)brow * TT_ + t) * 7;
        #pragma unroll
        for (int j = 1; j < 8; ++j) v[j] = (f16)cp[j - 1];
      }
      *(half8*)&lds[slot][tid * 8] = v;
    } else {
      gload16(src + (size_t)kb * 16384 + mb2 * 4096 + tid * 8, &lds[slot][tid * 8]);
    }
    // B-half (16KB = 4 panels): 2 passes x 512 threads x 16B
    {
      const int e0 = tid, e1 = tid + 512;
      gload16(Wt + ((size_t)((nb2 * 4 + (e0 >> 8)) * KB + kb)) * 2048 + (e0 & 255) * 8,
              &lds[slot][4096 + e0 * 8]);
      gload16(Wt + ((size_t)((nb2 * 4 + (e1 >> 8)) * KB + kb)) * 2048 + (e1 & 255) * 8,
              &lds[slot][4096 + e1 * 8]);
    }
  };
  auto stage_round = [&](int r) {          // 2 slabs; clamp => constant vm counts (6/lane)
    #pragma unroll
    for (int j = 0; j < 2; ++j) {
      int kb = 2 * r + j;
      if (kb >= KB) kb = KB - 1;           // phantom dup (l==0 odd tail only)
      stage_slab((r % 3) * 2 + j, kb);
    }
  };

  f32x4 acc[4][8];
  #pragma unroll
  for (int m = 0; m < 4; ++m)
    #pragma unroll
    for (int n = 0; n < 8; ++n) { acc[m][n][0]=0.f; acc[m][n][1]=0.f; acc[m][n][2]=0.f; acc[m][n][3]=0.f; }

  const int R = (KB + 1) >> 1;
  stage_round(0); stage_round(1);
  for (int i = 0; i < R; ++i) {
    if (i < R - 1) WAITBAR(6); else WAITBAR(0);
    const int kb = 2 * i + kg;
    const int slot = (i % 3) * 2 + kg;
    const half8* A  = (const half8*)&lds[slot][0];
    const half8* Bp = (const half8*)&lds[slot][4096];
    const bool live = (kb < KB);           // wave-uniform
    half8 a0, a1, a2, a3;
    half8 b0, b1, b2, b3, b4, b5, b6, b7;
    if (live) {
      a0 = A[(mg * 4 + 0) * 64 + ln];
      a1 = A[(mg * 4 + 1) * 64 + ln];
      a2 = A[(mg * 4 + 2) * 64 + ln];
      a3 = A[(mg * 4 + 3) * 64 + ln];
      const int nb0 = ng * 512 + ln;
      b0 = Bp[nb0];        b1 = Bp[nb0 + 64];  b2 = Bp[nb0 + 128]; b3 = Bp[nb0 + 192];
      b4 = Bp[nb0 + 256];  b5 = Bp[nb0 + 320]; b6 = Bp[nb0 + 384]; b7 = Bp[nb0 + 448];
    }
    if (i + 2 < R) stage_round(i + 2);
    if (live) {
      acc[0][0] = __builtin_amdgcn_mfma_f32_16x16x32_f16(a0, b0, acc[0][0], 0, 0, 0);
      acc[0][1] = __builtin_amdgcn_mfma_f32_16x16x32_f16(a0, b1, acc[0][1], 0, 0, 0);
      acc[0][2] = __builtin_amdgcn_mfma_f32_16x16x32_f16(a0, b2, acc[0][2], 0, 0, 0);
      acc[0][3] = __builtin_amdgcn_mfma_f32_16x16x32_f16(a0, b3, acc[0][3], 0, 0, 0);
      acc[0][4] = __builtin_amdgcn_mfma_f32_16x16x32_f16(a0, b4, acc[0][4], 0, 0, 0);
      acc[0][5] = __builtin_amdgcn_mfma_f32_16x16x32_f16(a0, b5, acc[0][5], 0, 0, 0);
      acc[0][6] = __builtin_amdgcn_mfma_f32_16x16x32_f16(a0, b6, acc[0][6], 0, 0, 0);
      acc[0][7] = __builtin_amdgcn_mfma_f32_16x16x32_f16(a0, b7, acc[0][7], 0, 0, 0);
      acc[1][0] = __builtin_amdgcn_mfma_f32_16x16x32_f16(a1, b0, acc[1][0], 0, 0, 0);
      acc[1][1] = __builtin_amdgcn_mfma_f32_16x16x32_f16(a1, b1, acc[1][1], 0, 0, 0);
      acc[1][2] = __builtin_amdgcn_mfma_f32_16x16x32_f16(a1, b2, acc[1][2], 0, 0, 0);
      acc[1][3] = __builtin_amdgcn_mfma_f32_16x16x32_f16(a1, b3, acc[1][3], 0, 0, 0);
      acc[1][4] = __builtin_amdgcn_mfma_f32_16x16x32_f16(a1, b4, acc[1][4], 0, 0, 0);
      acc[1][5] = __builtin_amdgcn_mfma_f32_16x16x32_f16(a1, b5, acc[1][5], 0, 0, 0);
      acc[1][6] = __builtin_amdgcn_mfma_f32_16x16x32_f16(a1, b6, acc[1][6], 0, 0, 0);
      acc[1][7] = __builtin_amdgcn_mfma_f32_16x16x32_f16(a1, b7, acc[1][7], 0, 0, 0);
      acc[2][0] = __builtin_amdgcn_mfma_f32_16x16x32_f16(a2, b0, acc[2][0], 0, 0, 0);
      acc[2][1] = __builtin_amdgcn_mfma_f32_16x16x32_f16(a2, b1, acc[2][1], 0, 0, 0);
      acc[2][2] = __builtin_amdgcn_mfma_f32_16x16x32_f16(a2, b2, acc[2][2], 0, 0, 0);
      acc[2][3] = __builtin_amdgcn_mfma_f32_16x16x32_f16(a2, b3, acc[2][3], 0, 0, 0);
      acc[2][4] = __builtin_amdgcn_mfma_f32_16x16x32_f16(a2, b4, acc[2][4], 0, 0, 0);
      acc[2][5] = __builtin_amdgcn_mfma_f32_16x16x32_f16(a2, b5, acc[2][5], 0, 0, 0);
      acc[2][6] = __builtin_amdgcn_mfma_f32_16x16x32_f16(a2, b6, acc[2][6], 0, 0, 0);
      acc[2][7] = __builtin_amdgcn_mfma_f32_16x16x32_f16(a2, b7, acc[2][7], 0, 0, 0);
      acc[3][0] = __builtin_amdgcn_mfma_f32_16x16x32_f16(a3, b0, acc[3][0], 0, 0, 0);
      acc[3][1] = __builtin_amdgcn_mfma_f32_16x16x32_f16(a3, b1, acc[3][1], 0, 0, 0);
      acc[3][2] = __builtin_amdgcn_mfma_f32_16x16x32_f16(a3, b2, acc[3][2], 0, 0, 0);
      acc[3][3] = __builtin_amdgcn_mfma_f32_16x16x32_f16(a3, b3, acc[3][3], 0, 0, 0);
      acc[3][4] = __builtin_amdgcn_mfma_f32_16x16x32_f16(a3, b4, acc[3][4], 0, 0, 0);
      acc[3][5] = __builtin_amdgcn_mfma_f32_16x16x32_f16(a3, b5, acc[3][5], 0, 0, 0);
      acc[3][6] = __builtin_amdgcn_mfma_f32_16x16x32_f16(a3, b6, acc[3][6], 0, 0, 0);
      acc[3][7] = __builtin_amdgcn_mfma_f32_16x16x32_f16(a3, b7, acc[3][7], 0, 0, 0);
    }
  }

  // ---- 2-way kg reduction via LDS overlay (slabs dead; vmcnt==0)
  __syncthreads();
  float* red = (float*)&lds[0][0];         // 4 waves x 32KB = 128KB
  if (kg == 1) {
    #pragma unroll
    for (int m = 0; m < 4; ++m)
      #pragma unroll
      for (int n = 0; n < 8; ++n)
        *(f32x4*)&red[(w - 4) * 8192 + (m * 8 + n) * 256 + ln * 4] = acc[m][n];
  }
  __syncthreads();
  if (kg == 0) {
    #pragma unroll
    for (int m = 0; m < 4; ++m)
      #pragma unroll
      for (int n = 0; n < 8; ++n) {
        f32x4 pv = *(const f32x4*)&red[w * 8192 + (m * 8 + n) * 256 + ln * 4];
        acc[m][n][0] += pv[0]; acc[m][n][1] += pv[1]; acc[m][n][2] += pv[2]; acc[m][n][3] += pv[3];
      }

    // ---- epilogue (kg=0 waves): wave (mg,ng) owns M64 x 2 panels (32 h-cols)
    #pragma unroll
    for (int jp = 0; jp < 2; ++jp) {
      const int col = (nb2 * 4 + 2 * ng + jp) * 16 + (ln & 15);
      const float bi  = bias4[col];
      const float bff = bias4[1024 + col];
      const float bgg = bias4[2048 + col];
      const float bo  = bias4[3072 + col];
      const float wl  = (l == 3) ? P.Wl[col] : 0.f;
      #pragma unroll
      for (int m = 0; m < 4; ++m) {
        const int rowb = m0 + (mg * 4 + m) * 16 + (ln >> 4) * 4;
        #pragma unroll
        for (int r = 0; r < 4; ++r) {
          const int row = rowb + r;
          float gi = acc[m][jp * 4 + 0][r] + bi;
          float gf = acc[m][jp * 4 + 1][r] + bff;
          float gg = acc[m][jp * 4 + 2][r] + bgg;
          float go = acc[m][jp * 4 + 3][r] + bo;
          float* cp = cst + (size_t)row * 1024 + col;
          float cn = sigf(gf) * (*cp) + sigf(gi) * tanhf_(gg);
          float h  = sigf(go) * tanhf_(cn);
          *cp = cn;
          f16 hh = (f16)h;
          selfd[haddr(koff + col, row)] = hh;
          if (l < 3) {
            nextd[haddr(col, row)] = hh;
          } else {
            float val = h * wl;
            val += __shfl_xor(val, 1);
            val += __shfl_xor(val, 2);
            val += __shfl_xor(val, 4);
            val += __shfl_xor(val, 8);
            if ((ln & 15) == 0) atomicAdd(P.out + (size_t)row * TT_ + t, val);
          }
        }
      }
    }
  }
}

// ============================================================================
// Small-tile kernel (R4/R8-proven): used for the serial FUTURE phase.
// ============================================================================
__global__ __launch_bounds__(512) void lstm_cells(PP P, int d, int lbeg, int lend, int tlim)
{
  __shared__ f16 lds[NSLOT][6144];  // per slab: A = 4096 halves (8KB), B = 2048 halves (4KB)
  const int tid = threadIdx.x;
  const int ln = tid & 63, w = tid >> 6;
  const int mg = w & 1, kg = w >> 1;        // split-K wave grid: 2 m-groups x 4 k-groups
  const int nb = blockIdx.x & 63, mb = blockIdx.x >> 6;
  const int m0 = mb * 128, n0 = nb * 16;

  for (int l = lbeg; l <= lend; ++l) {
    const int t = d - l;
    if (t < 0 || t >= tlim) continue;

    const int p = t & 1, q = p ^ 1;
    const f16* __restrict__ Wt = P.Wt[l];
    const int KB   = (l == 0) ? KB0 : KBR;
    const int mode = (l == 0) ? 0 : ((l == 3) ? 2 : 1);
    const int koff = (l == 0) ? 32 : 1024;
    const f16* __restrict__ src   = P.xh[l][p];
    f16* __restrict__ selfd       = P.xh[l][q];
    f16* __restrict__ nextd       = (l < 3) ? P.xh[l + 1][p] : nullptr;
    const float* __restrict__ bias4 = P.bias + l * 4096;
    float* __restrict__ cst = P.cst + (size_t)l * 524288;

    if (mode == 0 && nb == 0 && tid < 128) P.out[(size_t)(m0 + tid) * TT_ + t] = P.blp[0];

    auto stage_slab = [&](int slot, int kb) {
      if (mode == 0 && kb == 0) {
        int mf = tid >> 6, r = ln & 15, kgrp = ln >> 4;
        int brow = m0 + mf * 16 + r;
        half8 v;
        #pragma unroll
        for (int j = 0; j < 8; ++j) v[j] = (f16)0.f;
        if (kgrp == 0) {
          float x0 = (t < T_) ? P.input[brow * T_ + t] : P.out[(size_t)brow * TT_ + (t - 1)];
          v[0] = (f16)x0;
          const float* cp = P.cov + ((size_t)brow * TT_ + t) * 7;
          #pragma unroll
          for (int j = 1; j < 8; ++j) v[j] = (f16)cp[j - 1];
        }
        *(half8*)&lds[slot][tid * 8] = v;
      } else {
        gload16(src + (size_t)kb * 16384 + mb * 4096 + tid * 8, &lds[slot][tid * 8]);
      }
      if (tid < 256)
        gload16(Wt + ((size_t)(nb * KB + kb)) * 2048 + tid * 8, &lds[slot][4096 + tid * 8]);
    };
    auto stage_round = [&](int r) {
      int base = (r % 3) * 4;
      #pragma unroll
      for (int j = 0; j < 4; ++j) {
        int kb = r * 4 + j;
        if (kb >= KB) kb = KB - 1;
        stage_slab(base + j, kb);
      }
    };

    f32x4 acc[4][4];
    #pragma unroll
    for (int m = 0; m < 4; ++m)
      #pragma unroll
      for (int g = 0; g < 4; ++g) { acc[m][g][0]=0.f; acc[m][g][1]=0.f; acc[m][g][2]=0.f; acc[m][g][3]=0.f; }

    const int R = (KB + 3) >> 2;
    stage_round(0); stage_round(1);
    for (int i = 0; i < R; ++i) {
      if (i < R - 1) { if (w < 4) WAITBAR(8); else WAITBAR(4); }
      else           { WAITBAR(0); }
      const int kb = i * 4 + kg;
      const int slot = (i % 3) * 4 + kg;
      const half8* A  = (const half8*)&lds[slot][0];
      const half8* Bp = (const half8*)&lds[slot][4096];
      const bool live = (kb < KB);
      half8 a0, a1, a2, a3, b0, b1, b2, b3;
      if (live) {
        a0 = A[(mg * 4 + 0) * 64 + ln];
        a1 = A[(mg * 4 + 1) * 64 + ln];
        a2 = A[(mg * 4 + 2) * 64 + ln];
        a3 = A[(mg * 4 + 3) * 64 + ln];
        b0 = Bp[ln]; b1 = Bp[64 + ln]; b2 = Bp[128 + ln]; b3 = Bp[192 + ln];
      }
      if (i + 2 < R) stage_round(i + 2);
      if (live) {
        acc[0][0] = __builtin_amdgcn_mfma_f32_16x16x32_f16(a0, b0, acc[0][0], 0, 0, 0);
        acc[0][1] = __builtin_amdgcn_mfma_f32_16x16x32_f16(a0, b1, acc[0][1], 0, 0, 0);
        acc[0][2] = __builtin_amdgcn_mfma_f32_16x16x32_f16(a0, b2, acc[0][2], 0, 0, 0);
        acc[0][3] = __builtin_amdgcn_mfma_f32_16x16x32_f16(a0, b3, acc[0][3], 0, 0, 0);
        acc[1][0] = __builtin_amdgcn_mfma_f32_16x16x32_f16(a1, b0, acc[1][0], 0, 0, 0);
        acc[1][1] = __builtin_amdgcn_mfma_f32_16x16x32_f16(a1, b1, acc[1][1], 0, 0, 0);
        acc[1][2] = __builtin_amdgcn_mfma_f32_16x16x32_f16(a1, b2, acc[1][2], 0, 0, 0);
        acc[1][3] = __builtin_amdgcn_mfma_f32_16x16x32_f16(a1, b3, acc[1][3], 0, 0, 0);
        acc[2][0] = __builtin_amdgcn_mfma_f32_16x16x32_f16(a2, b0, acc[2][0], 0, 0, 0);
        acc[2][1] = __builtin_amdgcn_mfma_f32_16x16x32_f16(a2, b1, acc[2][1], 0, 0, 0);
        acc[2][2] = __builtin_amdgcn_mfma_f32_16x16x32_f16(a2, b2, acc[2][2], 0, 0, 0);
        acc[2][3] = __builtin_amdgcn_mfma_f32_16x16x32_f16(a2, b3, acc[2][3], 0, 0, 0);
        acc[3][0] = __builtin_amdgcn_mfma_f32_16x16x32_f16(a3, b0, acc[3][0], 0, 0, 0);
        acc[3][1] = __builtin_amdgcn_mfma_f32_16x16x32_f16(a3, b1, acc[3][1], 0, 0, 0);
        acc[3][2] = __builtin_amdgcn_mfma_f32_16x16x32_f16(a3, b2, acc[3][2], 0, 0, 0);
        acc[3][3] = __builtin_amdgcn_mfma_f32_16x16x32_f16(a3, b3, acc[3][3], 0, 0, 0);
      }
    }

    __syncthreads();
    float* red = (float*)&lds[0][0];
    #pragma unroll
    for (int m = 0; m < 4; ++m)
      #pragma unroll
      for (int g = 0; g < 4; ++g)
        *(f32x4*)&red[w * 4096 + (m * 4 + g) * 256 + ln * 4] = acc[m][g];
    __syncthreads();
    f32x4 facc[4];
    #pragma unroll
    for (int g = 0; g < 4; ++g) { facc[g][0]=0.f; facc[g][1]=0.f; facc[g][2]=0.f; facc[g][3]=0.f; }
    const int mgw = w >> 2, mlw = w & 3;
    #pragma unroll
    for (int kg2 = 0; kg2 < 4; ++kg2) {
      const int wsrc = kg2 * 2 + mgw;
      #pragma unroll
      for (int g = 0; g < 4; ++g) {
        f32x4 pv = *(const f32x4*)&red[wsrc * 4096 + (mlw * 4 + g) * 256 + ln * 4];
        facc[g][0] += pv[0]; facc[g][1] += pv[1]; facc[g][2] += pv[2]; facc[g][3] += pv[3];
      }
    }
    __syncthreads();

    const int col = n0 + (ln & 15);
    const int rowb = m0 + w * 16 + (ln >> 4) * 4;
    const float bi  = bias4[col];
    const float bff = bias4[1024 + col];
    const float bgg = bias4[2048 + col];
    const float bo  = bias4[3072 + col];
    const float wl  = (mode == 2) ? P.Wl[col] : 0.f;
    #pragma unroll
    for (int r = 0; r < 4; ++r) {
      const int row = rowb + r;
      float gi = facc[0][r] + bi;
      float gf = facc[1][r] + bff;
      float gg = facc[2][r] + bgg;
      float go = facc[3][r] + bo;
      float* cp = cst + (size_t)row * 1024 + col;
      float cn = sigf(gf) * (*cp) + sigf(gi) * tanhf_(gg);
      float h  = sigf(go) * tanhf_(cn);
      *cp = cn;
      f16 hh = (f16)h;
      selfd[haddr(koff + col, row)] = hh;
      if (mode != 2) {
        nextd[haddr(col, row)] = hh;
      } else {
        float val = h * wl;
        val += __shfl_xor(val, 1);
        val += __shfl_xor(val, 2);
        val += __shfl_xor(val, 4);
        val += __shfl_xor(val, 8);
        if ((ln & 15) == 0) atomicAdd(P.out + (size_t)row * TT_ + t, val);
      }
    }
  }
}

__global__ void zero_ws(uint4v* pz, int n)   // zero xh buffers + cell state
{
  int i = blockIdx.x * 256 + threadIdx.x;
  if (i < n) { uint4v z; z[0] = 0u; z[1] = 0u; z[2] = 0u; z[3] = 0u; pz[i] = z; }
}

__global__ void pack_weights(const float* __restrict__ Wih0, const float* __restrict__ Whh0,
                             const float* __restrict__ Wihr, const float* __restrict__ Whhr,
                             f16* __restrict__ Wt0, f16* __restrict__ Wt1,
                             f16* __restrict__ Wt2, f16* __restrict__ Wt3)
{
  const int layer = blockIdx.y;
  const size_t e = (size_t)blockIdx.x * 256 + threadIdx.x;
  const int KB = layer ? KBR : KB0;
  if (e >= (size_t)64 * KB * 2048) return;
  const int panel = (int)(e >> 11), win = (int)(e & 2047);
  const int g = win >> 9, lane = (win >> 3) & 63, j = win & 7;
  const int nb = panel / KB, kb = panel - nb * KB;
  const int n = nb * 16 + (lane & 15);
  const int k = kb * 32 + (lane >> 4) * 8 + j;
  const int jr = g * 1024 + n;                       // row in [4H][*] weight (gate-major)
  float v;
  if (layer == 0) {
    if (k < 8)       v = Wih0[jr * 8 + k];
    else if (k < 32) v = 0.f;
    else             v = Whh0[(size_t)jr * 1024 + (k - 32)];
  } else {
    const size_t base = (size_t)(layer - 1) * 4096 * 1024 + (size_t)jr * 1024;
    v = (k < 1024) ? Wihr[base + k] : Whhr[base + (k - 1024)];
  }
  f16 hv = (f16)v;
  if      (layer == 0) Wt0[e] = hv;
  else if (layer == 1) Wt1[e] = hv;
  else if (layer == 2) Wt2[e] = hv;
  else                 Wt3[e] = hv;
}

__global__ void pack_bias(const float* __restrict__ bih0, const float* __restrict__ bhh0,
                          const float* __restrict__ bihr, const float* __restrict__ bhhr,
                          float* __restrict__ bias)
{
  const int idx = blockIdx.x * 256 + threadIdx.x;    // 16384 = 4 layers x 4096
  const int lyr = idx >> 12, j = idx & 4095;
  bias[idx] = (lyr == 0) ? (bih0[j] + bhh0[j])
                         : (bihr[(lyr - 1) * 4096 + j] + bhhr[(lyr - 1) * 4096 + j]);
}

extern "C" void kernel_launch(void* const* d_in, const int* in_sizes, int n_in,
                              void* d_out, int out_size, void* d_ws, size_t ws_size,
                              hipStream_t stream)
{
  const float* input = (const float*)d_in[0];
  const float* cov   = (const float*)d_in[1];
  const float* Wih0  = (const float*)d_in[2];
  const float* Whh0  = (const float*)d_in[3];
  const float* bih0  = (const float*)d_in[4];
  const float* bhh0  = (const float*)d_in[5];
  const float* Wihr  = (const float*)d_in[6];
  const float* Whhr  = (const float*)d_in[7];
  const float* bihr  = (const float*)d_in[8];
  const float* bhhr  = (const float*)d_in[9];
  const float* Wl    = (const float*)d_in[10];
  const float* blp   = (const float*)d_in[11];
  float* out = (float*)d_out;
  char* ws = (char*)d_ws;

  // workspace layout (bytes): unchanged from R8.
  const size_t XH0 = 1081344, XHR = 2097152;
  PP Pv;
  Pv.xh[0][0] = (f16*)(ws);            Pv.xh[0][1] = (f16*)(ws + XH0);
  Pv.xh[1][0] = (f16*)(ws + 2162688);  Pv.xh[1][1] = (f16*)(ws + 2162688 + XHR);
  Pv.xh[2][0] = (f16*)(ws + 6356992);  Pv.xh[2][1] = (f16*)(ws + 6356992 + XHR);
  Pv.xh[3][0] = (f16*)(ws + 10551296); Pv.xh[3][1] = (f16*)(ws + 10551296 + XHR);
  Pv.cst     = (float*)(ws + 14745600);
  float* bias = (float*)(ws + 23134208);
  f16* Wt0 = (f16*)(ws + 23199744);
  f16* Wt1 = (f16*)(ws + 31850496);
  f16* Wt2 = (f16*)(ws + 48627712);
  f16* Wt3 = (f16*)(ws + 65404928);
  Pv.Wt[0] = Wt0; Pv.Wt[1] = Wt1; Pv.Wt[2] = Wt2; Pv.Wt[3] = Wt3;
  Pv.bias = bias; Pv.input = input; Pv.cov = cov;
  Pv.Wl = Wl; Pv.blp = blp; Pv.out = out;

  pack_weights<<<dim3(32768, 4), 256, 0, stream>>>(Wih0, Whh0, Wihr, Whhr, Wt0, Wt1, Wt2, Wt3);
  pack_bias<<<64, 256, 0, stream>>>(bih0, bhh0, bihr, bhhr, bias);
  zero_ws<<<5648, 256, 0, stream>>>((uint4v*)ws, 23134208 / 16);

  // Conditioning (t < 256): anti-diagonal wavefront, 4 cells x 64 big-tile blocks
  // in PARALLEL per dispatch (256 blocks, 1/CU).
  for (int dg = 0; dg <= 258; ++dg)
    lstm_cells_big<<<256, 512, 0, stream>>>(Pv, dg);
  // Future (t >= 256): out-feedback serializes; one small-tile cell per dispatch.
  for (int t = T_; t < TT_; ++t)
    for (int l = 0; l < 4; ++l)
      lstm_cells<<<256, 512, 0, stream>>>(Pv, t + l, l, l, TT_);
}